// Round 6
// baseline (1165.121 us; speedup 1.0000x reference)
//
#include <hip/hip_runtime.h>

#define SEQn 33
#define Fn   20480
#define Hn   900
#define Bn   2
#define WVn  100
#define OBJn 35
#define RELn 82
#define G4n  3600
#define Mn   66
#define KSn  2
#define KSL  (Fn/KSn)     // 10240
#define RBn  225          // row-blocks in K1
#define RPB  16           // rows per K1 block
#define NBLK 225
#define NITV 37

__device__ __forceinline__ float sigf(float v){ return 1.f/(1.f+expf(-v)); }
__device__ __forceinline__ float dot4(float4 a, float4 b){ return a.x*b.x+a.y*b.y+a.z*b.z+a.w*b.w; }
__device__ __forceinline__ float wred(float v){
  #pragma unroll
  for (int d = 32; d >= 1; d >>= 1) v += __shfl_xor(v, d, 64);
  return v;
}
// coherent (agent-scope, cache-bypassing) scalar access for cross-block data
__device__ __forceinline__ float gload(const float* p){
  return __hip_atomic_load((const float*)p, __ATOMIC_RELAXED, __HIP_MEMORY_SCOPE_AGENT);
}
__device__ __forceinline__ void gstore(float* p, float v){
  __hip_atomic_store(p, v, __ATOMIC_RELAXED, __HIP_MEMORY_SCOPE_AGENT);
}

// lightweight grid barrier: relaxed agent atomics only (proven round 5)
__device__ __forceinline__ void gbar(unsigned* bar){
  __syncthreads();
  if (threadIdx.x == 0) {
    unsigned g = __hip_atomic_load(&bar[0], __ATOMIC_RELAXED, __HIP_MEMORY_SCOPE_AGENT);
    unsigned cnt = __hip_atomic_fetch_add(&bar[32], 1u, __ATOMIC_RELAXED, __HIP_MEMORY_SCOPE_AGENT);
    if (cnt == (unsigned)(NBLK-1)) {
      __hip_atomic_store(&bar[32], 0u, __ATOMIC_RELAXED, __HIP_MEMORY_SCOPE_AGENT);
      asm volatile("s_waitcnt vmcnt(0)" ::: "memory");
      __hip_atomic_store(&bar[0], g+1u, __ATOMIC_RELAXED, __HIP_MEMORY_SCOPE_AGENT);
    } else {
      unsigned cur;
      do {
        __builtin_amdgcn_s_sleep(8);
        cur = __hip_atomic_load(&bar[0], __ATOMIC_RELAXED, __HIP_MEMORY_SCOPE_AGENT);
      } while (cur == g);
    }
  }
  __syncthreads();
}

// ---------------- K1: G1p[ks][r][m] = partial_k x[m][k]*w_ih1[r][k] (+biases at ks==0)
// 450 blocks, 256 thr. Register-staged x (issue early, ds_write late) — no vmcnt(0) stall.
__global__ __launch_bounds__(256) void k_gemm1(
    const float* __restrict__ x, const float* __restrict__ w1,
    const float* __restrict__ bi, const float* __restrict__ bh,
    float* __restrict__ G1p, unsigned* __restrict__ bar)
{
  const int tid = threadIdx.x;
  if (blockIdx.x == 0 && tid == 0) {   // init barrier for k_rec (each replay)
    __hip_atomic_store(&bar[0], 0u, __ATOMIC_RELAXED, __HIP_MEMORY_SCOPE_AGENT);
    __hip_atomic_store(&bar[32], 0u, __ATOMIC_RELAXED, __HIP_MEMORY_SCOPE_AGENT);
  }
  __shared__ float xs[2][Mn*128];
  const int rb = blockIdx.x % RBn;
  const int ks = blockIdx.x / RBn;
  const int kp = tid & 31;
  const int rg = tid >> 5;        // 0..7
  const int rowgrp = rg >> 1;     // 0..3
  const int mbase = (rg & 1)*33;
  const int rbase = rb*RPB + rowgrp*4;
  const int kofs = ks*KSL;

  float acc[4][33];
  #pragma unroll
  for (int a = 0; a < 4; ++a)
    #pragma unroll
    for (int b = 0; b < 33; ++b) acc[a][b] = 0.f;

  float4 xr[9];
  // prologue: stage chunk 0
  #pragma unroll
  for (int u = 0; u < 9; ++u) {
    const int i = tid + u*256;
    if (i < Mn*32) {
      const int m = i >> 5, q = i & 31;
      xr[u] = *(const float4*)(x + (size_t)m*Fn + kofs + q*4);
    }
  }
  #pragma unroll
  for (int u = 0; u < 9; ++u) {
    const int i = tid + u*256;
    if (i < Mn*32) *(float4*)&xs[0][i*4] = xr[u];
  }
  float4 wc[4];
  #pragma unroll
  for (int ri = 0; ri < 4; ++ri)
    wc[ri] = *(const float4*)(w1 + (size_t)(rbase+ri)*Fn + kofs + kp*4);
  __syncthreads();

  const int NC = KSL/128;   // 80
  for (int c = 0; c < NC; ++c) {
    const int buf = c & 1;
    float4 wn[4];
    if (c+1 < NC) {       // issue next chunk's loads EARLY (regs)
      const int k0n = kofs + (c+1)*128;
      #pragma unroll
      for (int u = 0; u < 9; ++u) {
        const int i = tid + u*256;
        if (i < Mn*32) {
          const int m = i >> 5, q = i & 31;
          xr[u] = *(const float4*)(x + (size_t)m*Fn + k0n + q*4);
        }
      }
      #pragma unroll
      for (int ri = 0; ri < 4; ++ri)
        wn[ri] = *(const float4*)(w1 + (size_t)(rbase+ri)*Fn + k0n + kp*4);
    }
    // compute chunk c (loads for c+1 fly underneath)
    #pragma unroll
    for (int mi = 0; mi < 33; ++mi) {
      float4 xv = *(const float4*)&xs[buf][(mbase+mi)*128 + kp*4];
      #pragma unroll
      for (int ri = 0; ri < 4; ++ri) acc[ri][mi] += dot4(wc[ri], xv);
    }
    if (c+1 < NC) {       // write LDS LATE (auto-waits only on own loads)
      #pragma unroll
      for (int u = 0; u < 9; ++u) {
        const int i = tid + u*256;
        if (i < Mn*32) *(float4*)&xs[buf^1][i*4] = xr[u];
      }
      wc[0]=wn[0]; wc[1]=wn[1]; wc[2]=wn[2]; wc[3]=wn[3];
    }
    __syncthreads();
  }

  #pragma unroll
  for (int ri = 0; ri < 4; ++ri)
    #pragma unroll
    for (int mi = 0; mi < 33; ++mi) {
      float v = acc[ri][mi];
      v += __shfl_xor(v, 16, 64);
      v += __shfl_xor(v, 8, 64);
      v += __shfl_xor(v, 4, 64);
      v += __shfl_xor(v, 2, 64);
      v += __shfl_xor(v, 1, 64);
      acc[ri][mi] = v;
    }
  if (kp == 0) {
    #pragma unroll
    for (int ri = 0; ri < 4; ++ri) {
      const int r = rbase + ri;
      const float bsum = (ks == 0) ? (bi[r] + bh[r]) : 0.f;
      for (int mi = 0; mi < 33; ++mi)
        G1p[((size_t)ks*G4n + r)*Mn + mbase + mi] = acc[ri][mi] + bsum;
    }
  }
}

// ---------------- K2 (cooperative, 225 x 512): interval i = L1 step i ∥ L2 step i-1.
// L2 weights register-prefetched one interval ahead (latency hidden under barrier+dots).
__global__ __launch_bounds__(512) void k_rec(
    const float* __restrict__ G1p, float* __restrict__ out1, float* __restrict__ h2buf,
    const float* __restrict__ whh1,
    const float* __restrict__ wih2, const float* __restrict__ whh2,
    const float* __restrict__ bih2, const float* __restrict__ bhh2,
    const float* __restrict__ wobj1, const float* __restrict__ bobj1,
    const float* __restrict__ wrel,  const float* __restrict__ brel,
    const float* __restrict__ wobj2, const float* __restrict__ bobj2,
    const float* __restrict__ embed, float* __restrict__ dout,
    unsigned* __restrict__ bar)
{
  __shared__ float hls[Bn][904];    // out1[src] (shared by L1-dot and L2-dot)
  __shared__ float h2l[Bn][904];    // L2 h_{s-1}
  __shared__ float wvls[Bn][104];   // word vector
  __shared__ float gls[16][68];     // G1 (summed K-partials) for this block's rhos
  __shared__ float bls[SEQn][16];   // layer-2 bias sums per step
  __shared__ float gexA[16][Bn], gexB[16][Bn];
  __shared__ float cA[4][Bn], cB[4][Bn];
  __shared__ float red[4];
  __shared__ int idxls[Bn];

  const int tid = threadIdx.x;
  const int blk = blockIdx.x;
  const int j0 = blk * 4;
  const int wv_ = tid >> 6;
  const int lane = tid & 63;

  if (tid < 8) {
    const int jj = tid >> 1, m = tid & 1;
    cA[jj][m] = 0.f; cB[jj][m] = 0.f;
    gstore(h2buf + (size_t)m*Hn + j0 + jj, 0.f);   // buffer 0
  }

  // prologue staging: G1 sums + biases into LDS (one-time)
  for (int q = tid; q < 16*Mn; q += 512) {
    const int rho = q / Mn, t = q % Mn;
    const int gate = rho >> 2, jj = rho & 3;
    const size_t rA = (size_t)gate*Hn + j0 + jj;
    gls[rho][t] = G1p[rA*Mn + t] + G1p[((size_t)G4n + rA)*Mn + t];
  }
  for (int q = tid; q < SEQn*16; q += 512) {
    const int s = q / 16, rho = q % 16;
    const int gate = rho >> 2, jj = rho & 3;
    const size_t ro = (size_t)s*G4n + (size_t)gate*Hn + j0 + jj;
    bls[s][rho] = bih2[ro] + bhh2[ro];
  }

  float4 wAreg[2][4];
  #pragma unroll
  for (int ri = 0; ri < 2; ++ri) {
    const int rho = wv_*2 + ri;
    const int gate = rho >> 2, jj = rho & 3;
    const size_t row = (size_t)gate*Hn + j0 + jj;
    #pragma unroll
    for (int e = 0; e < 4; ++e) {
      const int k = lane*4 + e*256;
      wAreg[ri][e] = (k <= Hn-4) ? *(const float4*)(whh1 + row*Hn + k)
                                 : make_float4(0.f,0.f,0.f,0.f);
    }
  }

  // L2 weight prefetch registers (one interval ahead)
  float4 wiR[2][4], whR[2][4];
  #define ISSUE_W(sp)                                                        \
    { _Pragma("unroll")                                                      \
      for (int ri = 0; ri < 2; ++ri) {                                       \
        const int rho = wv_*2 + ri;                                          \
        const int gate = rho >> 2, jj = rho & 3;                             \
        const size_t ro = (size_t)(sp)*G4n + (size_t)gate*Hn + j0 + jj;      \
        const float* wI = wih2 + ro*1000;                                    \
        const float* wH = whh2 + ro*Hn;                                      \
        _Pragma("unroll")                                                    \
        for (int e = 0; e < 4; ++e) {                                        \
          const int k = lane*4 + e*256;                                      \
          if (k <= 996) wiR[ri][e] = *(const float4*)(wI + k);               \
          if (k <= 896) whR[ri][e] = *(const float4*)(wH + k);               \
        }                                                                    \
      }                                                                      \
    }
  ISSUE_W(0);            // for interval i=1 (s=0)

  for (int i = 0; i < NITV; ++i) {
    const bool hasA = (i <= 32);
    const int  s = (i >= 1 && i <= 31) ? (i-1) : (i == 33) ? 31 : (i == 35) ? 32 : -1;
    const bool hasB = (s >= 0);

    if (i == 33 || i == 35) {       // wave-parallel argmax + word-vector fetch
      if (wv_ < 2) {
        const int m = wv_;
        const int nout = (i == 33) ? OBJn : RELn;
        const int off = (i == 33) ? 0 : Bn*OBJn;
        float v = -1e30f; int idx = 0;
        for (int o = lane; o < nout; o += 64) {
          float t = gload(dout + off + m*nout + o);
          if (t > v) { v = t; idx = o; }
        }
        #pragma unroll
        for (int d = 32; d >= 1; d >>= 1) {
          float ov = __shfl_xor(v, d, 64);
          int   oi = __shfl_xor(idx, d, 64);
          if (ov > v || (ov == v && oi < idx)) { v = ov; idx = oi; }
        }
        if (lane == 0) idxls[m] = idx + ((i == 35) ? OBJn : 0);
      }
      __syncthreads();
      for (int q = tid; q < Bn*104; q += 512) {
        const int m = q / 104, v4 = q % 104;
        wvls[m][v4] = (v4 < WVn) ? embed[(size_t)idxls[m]*WVn + v4] : 0.f;
      }
      __syncthreads();
    }

    // ---- stage h-state (coherent scalar loads)
    const bool stageH = hasA || (i == 35);
    const int  srcA = (i == 35) ? 32 : i-1;
    if (stageH) {
      for (int q = tid; q < 1808; q += 512) {
        const int m = q / 904, kk = q % 904;
        hls[m][kk] = (i > 0 && kk < 900)
          ? gload(out1 + ((size_t)srcA*Bn + m)*Hn + kk) : 0.f;
      }
    }
    if (hasB) {
      for (int q = tid; q < 1808; q += 512) {
        const int m = q / 904, kk = q % 904;
        h2l[m][kk] = (kk < 900)
          ? gload(h2buf + ((size_t)(s&1)*Bn + m)*Hn + kk) : 0.f;
      }
    }
    __syncthreads();

    if (hasA) {
      #pragma unroll
      for (int ri = 0; ri < 2; ++ri) {
        const int rho = wv_*2 + ri;
        float a0 = 0.f, a1 = 0.f;
        #pragma unroll
        for (int e = 0; e < 4; ++e) {
          const int k = lane*4 + e*256;
          if (k <= Hn-4) {
            a0 += dot4(wAreg[ri][e], *(const float4*)&hls[0][k]);
            a1 += dot4(wAreg[ri][e], *(const float4*)&hls[1][k]);
          }
        }
        a0 = wred(a0); a1 = wred(a1);
        if (lane == 0) {
          gexA[rho][0] = a0 + gls[rho][i*Bn + 0];
          gexA[rho][1] = a1 + gls[rho][i*Bn + 1];
        }
      }
    }

    if (hasB) {
      #pragma unroll
      for (int ri = 0; ri < 2; ++ri) {
        const int rho = wv_*2 + ri;
        float b0 = 0.f, b1 = 0.f;
        #pragma unroll
        for (int e = 0; e < 4; ++e) {
          const int k = lane*4 + e*256;
          if (k <= 896) {
            b0 += dot4(wiR[ri][e], *(const float4*)&hls[0][k]);
            b1 += dot4(wiR[ri][e], *(const float4*)&hls[1][k]);
            b0 += dot4(whR[ri][e], *(const float4*)&h2l[0][k]);
            b1 += dot4(whR[ri][e], *(const float4*)&h2l[1][k]);
          } else if (k >= 900 && k <= 996 && s >= SEQn-2) {
            b0 += dot4(wiR[ri][e], *(const float4*)&wvls[0][k-900]);
            b1 += dot4(wiR[ri][e], *(const float4*)&wvls[1][k-900]);
          }
        }
        b0 = wred(b0); b1 = wred(b1);
        if (lane == 0) {
          const float bb = bls[s][rho];
          gexB[rho][0] = b0 + bb;
          gexB[rho][1] = b1 + bb;
        }
      }
      if (s < 32) ISSUE_W(s+1);    // prefetch next step's weights (WAR-safe)
    }

    if (i == 32 || i == 34 || i == 36) {  // heads: obj1 / rel / obj2
      const int nout = (i == 34) ? RELn : OBJn;
      const float* wh  = (i == 32) ? wobj1 : (i == 34) ? wrel : wobj2;
      const float* bh_ = (i == 32) ? bobj1 : (i == 34) ? brel : bobj2;
      const int off = (i == 32) ? 0 : (i == 34) ? (Bn*OBJn) : (Bn*OBJn + Bn*RELn);
      const int hb = (i == 34) ? 0 : 1;
      if (blk < nout*Bn) {
        const int o = blk >> 1, m = blk & 1;
        float p = 0.f;
        if (tid < 225) {
          const float4 wv4 = *(const float4*)(wh + (size_t)o*Hn + tid*4);
          float* hp = h2buf + ((size_t)hb*Bn + m)*Hn + tid*4;
          p = wv4.x*gload(hp+0) + wv4.y*gload(hp+1)
            + wv4.z*gload(hp+2) + wv4.w*gload(hp+3);
        }
        if (wv_ < 4) {
          const float pr = wred(p);
          if (lane == 0) red[wv_] = pr;
        }
        __syncthreads();
        if (tid == 0)
          gstore(&dout[off + m*nout + o], red[0]+red[1]+red[2]+red[3] + bh_[o]);
      }
    }

    __syncthreads();
    if (tid < 8) {
      const int jj = tid >> 1, m = tid & 1;
      if (hasA) {
        const float cc = sigf(gexA[4+jj][m])*cA[jj][m]
                       + sigf(gexA[jj][m])*tanhf(gexA[8+jj][m]);
        cA[jj][m] = cc;
        gstore(out1 + ((size_t)i*Bn + m)*Hn + j0 + jj, sigf(gexA[12+jj][m])*tanhf(cc));
      }
      if (hasB) {
        const float cc = sigf(gexB[4+jj][m])*cB[jj][m]
                       + sigf(gexB[jj][m])*tanhf(gexB[8+jj][m]);
        cB[jj][m] = cc;
        gstore(h2buf + ((size_t)((s+1)&1)*Bn + m)*Hn + j0 + jj,
               sigf(gexB[12+jj][m])*tanhf(cc));
      }
    }

    if (i < NITV-1) gbar(bar);
  }
}

extern "C" void kernel_launch(void* const* d_in, const int* in_sizes, int n_in,
                              void* d_out, int out_size, void* d_ws, size_t ws_size,
                              hipStream_t stream)
{
  (void)in_sizes; (void)n_in; (void)out_size; (void)ws_size;
  const float* x     = (const float*)d_in[0];
  const float* wih1  = (const float*)d_in[1];
  const float* whh1  = (const float*)d_in[2];
  const float* bih1  = (const float*)d_in[3];
  const float* bhh1  = (const float*)d_in[4];
  const float* wih2  = (const float*)d_in[5];
  const float* whh2  = (const float*)d_in[6];
  const float* bih2  = (const float*)d_in[7];
  const float* bhh2  = (const float*)d_in[8];
  const float* wobj1 = (const float*)d_in[9];
  const float* bobj1 = (const float*)d_in[10];
  const float* wrel  = (const float*)d_in[11];
  const float* brel  = (const float*)d_in[12];
  const float* wobj2 = (const float*)d_in[13];
  const float* bobj2 = (const float*)d_in[14];
  const float* embed = (const float*)d_in[15];
  float* dout = (float*)d_out;

  float* ws = (float*)d_ws;
  float* G1p   = ws;                                  // 2*3600*66
  float* out1  = G1p + (size_t)KSn*G4n*Mn;            // 33*2*900
  float* h2buf = out1 + (size_t)SEQn*Bn*Hn;           // 2*2*900
  unsigned* bar = (unsigned*)(h2buf + (size_t)2*Bn*Hn);

  hipLaunchKernelGGL(k_gemm1, dim3(RBn*KSn), dim3(256), 0, stream,
                     x, wih1, bih1, bhh1, G1p, bar);

  void* args[17];
  args[0]  = (void*)&G1p;   args[1]  = (void*)&out1;  args[2]  = (void*)&h2buf;
  args[3]  = (void*)&whh1;  args[4]  = (void*)&wih2;  args[5]  = (void*)&whh2;
  args[6]  = (void*)&bih2;  args[7]  = (void*)&bhh2;  args[8]  = (void*)&wobj1;
  args[9]  = (void*)&bobj1; args[10] = (void*)&wrel;  args[11] = (void*)&brel;
  args[12] = (void*)&wobj2; args[13] = (void*)&bobj2; args[14] = (void*)&embed;
  args[15] = (void*)&dout;  args[16] = (void*)&bar;
  hipLaunchCooperativeKernel((void*)k_rec, dim3(NBLK), dim3(512), args, 0, stream);
}

// Round 7
// 564.581 us; speedup vs baseline: 2.0637x; 2.0637x over previous
//
#include <hip/hip_runtime.h>

#define SEQn 33
#define Fn   20480
#define Hn   900
#define Bn   2
#define WVn  100
#define OBJn 35
#define RELn 82
#define G4n  3600
#define Mn   66
#define NBLK 225
#define NITV 37

// ---- K1 MFMA geometry
#define KS1  16            // K-split
#define KSL1 (Fn/KS1)      // 1280
#define RB1  15            // row-blocks
#define RPB1 240           // rows per block (15 tiles of 16)
#define NC1  (KSL1/32)     // 40 chunks of K=32
#define WSTR 40            // LDS row stride in bf16 (32 data + 8 pad)

typedef __attribute__((ext_vector_type(8))) short bf16x8;
typedef __attribute__((ext_vector_type(4))) float f32x4;

__device__ __forceinline__ float sigf(float v){ return 1.f/(1.f+expf(-v)); }
__device__ __forceinline__ float dot4(float4 a, float4 b){ return a.x*b.x+a.y*b.y+a.z*b.z+a.w*b.w; }
__device__ __forceinline__ float wred(float v){
  #pragma unroll
  for (int d = 32; d >= 1; d >>= 1) v += __shfl_xor(v, d, 64);
  return v;
}
__device__ __forceinline__ float gload(const float* p){
  return __hip_atomic_load((const float*)p, __ATOMIC_RELAXED, __HIP_MEMORY_SCOPE_AGENT);
}
__device__ __forceinline__ void gstore(float* p, float v){
  __hip_atomic_store(p, v, __ATOMIC_RELAXED, __HIP_MEMORY_SCOPE_AGENT);
}
__device__ __forceinline__ unsigned short f2bf(float f){
  unsigned u = __float_as_uint(f);
  unsigned r = u + 0x7FFFu + ((u >> 16) & 1u);
  return (unsigned short)(r >> 16);
}
__device__ __forceinline__ float bf2f(unsigned short h){
  return __uint_as_float(((unsigned)h) << 16);
}

// lightweight grid barrier: relaxed agent atomics only (proven round 5)
__device__ __forceinline__ void gbar(unsigned* bar){
  __syncthreads();
  if (threadIdx.x == 0) {
    unsigned g = __hip_atomic_load(&bar[0], __ATOMIC_RELAXED, __HIP_MEMORY_SCOPE_AGENT);
    unsigned cnt = __hip_atomic_fetch_add(&bar[32], 1u, __ATOMIC_RELAXED, __HIP_MEMORY_SCOPE_AGENT);
    if (cnt == (unsigned)(NBLK-1)) {
      __hip_atomic_store(&bar[32], 0u, __ATOMIC_RELAXED, __HIP_MEMORY_SCOPE_AGENT);
      asm volatile("s_waitcnt vmcnt(0)" ::: "memory");
      __hip_atomic_store(&bar[0], g+1u, __ATOMIC_RELAXED, __HIP_MEMORY_SCOPE_AGENT);
    } else {
      unsigned cur;
      do {
        __builtin_amdgcn_s_sleep(8);
        cur = __hip_atomic_load(&bar[0], __ATOMIC_RELAXED, __HIP_MEMORY_SCOPE_AGENT);
      } while (cur == g);
    }
  }
  __syncthreads();
}

// ---------------- K1 (MFMA split-precision bf16): G1[r][m] += W[r,:]·X[m,:] over K-slice
// 240 blocks (15 rb x 16 ks), 320 thr (5 waves). Wave owns row-tiles {w, w+5, w+10} x 5 m-tiles.
__global__ __launch_bounds__(320) void k1_mfma(
    const float* __restrict__ x, const float* __restrict__ w1,
    float* __restrict__ G1, unsigned* __restrict__ bar)
{
  const int tid = threadIdx.x;
  if (blockIdx.x == 0 && tid == 0) {   // init k_rec barrier (each replay)
    __hip_atomic_store(&bar[0], 0u, __ATOMIC_RELAXED, __HIP_MEMORY_SCOPE_AGENT);
    __hip_atomic_store(&bar[32], 0u, __ATOMIC_RELAXED, __HIP_MEMORY_SCOPE_AGENT);
  }
  __shared__ unsigned short WhL[2][RPB1*WSTR], WlL[2][RPB1*WSTR];
  __shared__ unsigned short XhL[2][80*WSTR],  XlL[2][80*WSTR];

  const int rb = blockIdx.x % RB1;
  const int ks = blockIdx.x / RB1;
  const int r0 = rb * RPB1;
  const int kofs = ks * KSL1;
  const int wv_ = tid >> 6;        // 0..4
  const int lane = tid & 63;
  const int p = lane & 15;
  const int q = lane >> 4;

  f32x4 acc[3][5];
  #pragma unroll
  for (int rt = 0; rt < 3; ++rt)
    #pragma unroll
    for (int mt = 0; mt < 5; ++mt) acc[rt][mt] = (f32x4){0.f,0.f,0.f,0.f};

  float4 wr[6], xrg[2];

  #define ISSUE_STAGE(cc)                                                      \
    { const int kbase = kofs + (cc)*32;                                        \
      _Pragma("unroll")                                                        \
      for (int u = 0; u < 6; ++u) {                                            \
        const int idx = tid + u*320;                                           \
        const int row = idx >> 3, k4 = idx & 7;                                \
        wr[u] = *(const float4*)(w1 + (size_t)(r0+row)*Fn + kbase + k4*4);     \
      }                                                                        \
      _Pragma("unroll")                                                        \
      for (int u = 0; u < 2; ++u) {                                            \
        const int idx = tid + u*320;                                           \
        const int mrow = idx >> 3, k4 = idx & 7;                               \
        xrg[u] = (mrow < Mn)                                                   \
          ? *(const float4*)(x + (size_t)mrow*Fn + kbase + k4*4)               \
          : make_float4(0.f,0.f,0.f,0.f);                                      \
      }                                                                        \
    }

  #define CVTW(dsth, dstl, off, v)                                             \
    { const unsigned short h0=f2bf(v.x), h1=f2bf(v.y), h2=f2bf(v.z), h3=f2bf(v.w); \
      const unsigned short l0=f2bf(v.x-bf2f(h0)), l1=f2bf(v.y-bf2f(h1));       \
      const unsigned short l2=f2bf(v.z-bf2f(h2)), l3=f2bf(v.w-bf2f(h3));       \
      *(uint2*)&dsth[off] = make_uint2((unsigned)h0|((unsigned)h1<<16),        \
                                       (unsigned)h2|((unsigned)h3<<16));       \
      *(uint2*)&dstl[off] = make_uint2((unsigned)l0|((unsigned)l1<<16),        \
                                       (unsigned)l2|((unsigned)l3<<16));       \
    }

  #define WRITE_STAGE(bb)                                                     \
    { _Pragma("unroll")                                                       \
      for (int u = 0; u < 6; ++u) {                                           \
        const int idx = tid + u*320;                                          \
        const int row = idx >> 3, k4 = idx & 7;                               \
        CVTW(WhL[bb], WlL[bb], row*WSTR + k4*4, wr[u]);                       \
      }                                                                       \
      _Pragma("unroll")                                                       \
      for (int u = 0; u < 2; ++u) {                                           \
        const int idx = tid + u*320;                                          \
        const int mrow = idx >> 3, k4 = idx & 7;                              \
        CVTW(XhL[bb], XlL[bb], mrow*WSTR + k4*4, xrg[u]);                     \
      }                                                                       \
    }

  ISSUE_STAGE(0);
  WRITE_STAGE(0);
  __syncthreads();

  for (int c = 0; c < NC1; ++c) {
    const int buf = c & 1;
    if (c+1 < NC1) ISSUE_STAGE(c+1);

    bf16x8 Bh[5], Bl[5];
    #pragma unroll
    for (int mt = 0; mt < 5; ++mt) {
      const int moff = (mt*16 + p)*WSTR + q*8;
      Bh[mt] = *(const bf16x8*)&XhL[buf][moff];
      Bl[mt] = *(const bf16x8*)&XlL[buf][moff];
    }
    #pragma unroll
    for (int rt = 0; rt < 3; ++rt) {
      const int roff = ((wv_ + 5*rt)*16 + p)*WSTR + q*8;
      const bf16x8 Ah = *(const bf16x8*)&WhL[buf][roff];
      const bf16x8 Al = *(const bf16x8*)&WlL[buf][roff];
      #pragma unroll
      for (int mt = 0; mt < 5; ++mt) {
        acc[rt][mt] = __builtin_amdgcn_mfma_f32_16x16x32_bf16(Ah, Bh[mt], acc[rt][mt], 0, 0, 0);
        acc[rt][mt] = __builtin_amdgcn_mfma_f32_16x16x32_bf16(Ah, Bl[mt], acc[rt][mt], 0, 0, 0);
        acc[rt][mt] = __builtin_amdgcn_mfma_f32_16x16x32_bf16(Al, Bh[mt], acc[rt][mt], 0, 0, 0);
      }
    }

    if (c+1 < NC1) WRITE_STAGE(buf^1);
    __syncthreads();
  }

  // epilogue: D row = q*4+reg, col = p  ->  atomic-accumulate K-partials into G1
  #pragma unroll
  for (int rt = 0; rt < 3; ++rt)
    #pragma unroll
    for (int mt = 0; mt < 5; ++mt) {
      const int m = mt*16 + p;
      if (m < Mn) {
        #pragma unroll
        for (int r4 = 0; r4 < 4; ++r4) {
          const int grow = r0 + (wv_ + 5*rt)*16 + q*4 + r4;
          atomicAdd(&G1[(size_t)grow*Mn + m], acc[rt][mt][r4]);
        }
      }
    }
  #undef ISSUE_STAGE
  #undef WRITE_STAGE
  #undef CVTW
}

// ---------------- K2 (cooperative, 225 x 512): interval i = L1 step i ∥ L2 step i-1.
// L2 weights register-prefetched one interval ahead; custom relaxed-atomic barrier.
__global__ __launch_bounds__(512) void k_rec(
    const float* __restrict__ G1, float* __restrict__ out1, float* __restrict__ h2buf,
    const float* __restrict__ whh1,
    const float* __restrict__ wih2, const float* __restrict__ whh2,
    const float* __restrict__ bih2, const float* __restrict__ bhh2,
    const float* __restrict__ bih1, const float* __restrict__ bhh1,
    const float* __restrict__ wobj1, const float* __restrict__ bobj1,
    const float* __restrict__ wrel,  const float* __restrict__ brel,
    const float* __restrict__ wobj2, const float* __restrict__ bobj2,
    const float* __restrict__ embed, float* __restrict__ dout,
    unsigned* __restrict__ bar)
{
  __shared__ float hls[Bn][904];
  __shared__ float h2l[Bn][904];
  __shared__ float wvls[Bn][104];
  __shared__ float gls[16][68];
  __shared__ float bls[SEQn][16];
  __shared__ float gexA[16][Bn], gexB[16][Bn];
  __shared__ float cA[4][Bn], cB[4][Bn];
  __shared__ float red[4];
  __shared__ int idxls[Bn];

  const int tid = threadIdx.x;
  const int blk = blockIdx.x;
  const int j0 = blk * 4;
  const int wv_ = tid >> 6;
  const int lane = tid & 63;

  if (tid < 8) {
    const int jj = tid >> 1, m = tid & 1;
    cA[jj][m] = 0.f; cB[jj][m] = 0.f;
    gstore(h2buf + (size_t)m*Hn + j0 + jj, 0.f);   // buffer 0
  }

  // prologue staging: G1 (+layer-1 biases) and layer-2 bias sums into LDS
  for (int qq = tid; qq < 16*Mn; qq += 512) {
    const int rho = qq / Mn, t = qq % Mn;
    const int gate = rho >> 2, jj = rho & 3;
    const size_t rA = (size_t)gate*Hn + j0 + jj;
    gls[rho][t] = G1[rA*Mn + t] + bih1[rA] + bhh1[rA];
  }
  for (int qq = tid; qq < SEQn*16; qq += 512) {
    const int s = qq / 16, rho = qq % 16;
    const int gate = rho >> 2, jj = rho & 3;
    const size_t ro = (size_t)s*G4n + (size_t)gate*Hn + j0 + jj;
    bls[s][rho] = bih2[ro] + bhh2[ro];
  }

  float4 wAreg[2][4];
  #pragma unroll
  for (int ri = 0; ri < 2; ++ri) {
    const int rho = wv_*2 + ri;
    const int gate = rho >> 2, jj = rho & 3;
    const size_t row = (size_t)gate*Hn + j0 + jj;
    #pragma unroll
    for (int e = 0; e < 4; ++e) {
      const int k = lane*4 + e*256;
      wAreg[ri][e] = (k <= Hn-4) ? *(const float4*)(whh1 + row*Hn + k)
                                 : make_float4(0.f,0.f,0.f,0.f);
    }
  }

  // L2 weight prefetch registers (one interval ahead)
  float4 wiR[2][4], whR[2][4];
  #define ISSUE_W(sp)                                                        \
    { _Pragma("unroll")                                                      \
      for (int ri = 0; ri < 2; ++ri) {                                       \
        const int rho = wv_*2 + ri;                                          \
        const int gate = rho >> 2, jj = rho & 3;                             \
        const size_t ro = (size_t)(sp)*G4n + (size_t)gate*Hn + j0 + jj;      \
        const float* wI = wih2 + ro*1000;                                    \
        const float* wH = whh2 + ro*Hn;                                      \
        _Pragma("unroll")                                                    \
        for (int e = 0; e < 4; ++e) {                                        \
          const int k = lane*4 + e*256;                                      \
          if (k <= 996) wiR[ri][e] = *(const float4*)(wI + k);               \
          if (k <= 896) whR[ri][e] = *(const float4*)(wH + k);               \
        }                                                                    \
      }                                                                      \
    }
  ISSUE_W(0);

  for (int i = 0; i < NITV; ++i) {
    const bool hasA = (i <= 32);
    const int  s = (i >= 1 && i <= 31) ? (i-1) : (i == 33) ? 31 : (i == 35) ? 32 : -1;
    const bool hasB = (s >= 0);

    if (i == 33 || i == 35) {
      if (wv_ < 2) {
        const int m = wv_;
        const int nout = (i == 33) ? OBJn : RELn;
        const int off = (i == 33) ? 0 : Bn*OBJn;
        float v = -1e30f; int idx = 0;
        for (int o = lane; o < nout; o += 64) {
          float t = gload(dout + off + m*nout + o);
          if (t > v) { v = t; idx = o; }
        }
        #pragma unroll
        for (int d = 32; d >= 1; d >>= 1) {
          float ov = __shfl_xor(v, d, 64);
          int   oi = __shfl_xor(idx, d, 64);
          if (ov > v || (ov == v && oi < idx)) { v = ov; idx = oi; }
        }
        if (lane == 0) idxls[m] = idx + ((i == 35) ? OBJn : 0);
      }
      __syncthreads();
      for (int qq = tid; qq < Bn*104; qq += 512) {
        const int m = qq / 104, v4 = qq % 104;
        wvls[m][v4] = (v4 < WVn) ? embed[(size_t)idxls[m]*WVn + v4] : 0.f;
      }
      __syncthreads();
    }

    const bool stageH = hasA || (i == 35);
    const int  srcA = (i == 35) ? 32 : i-1;
    if (stageH) {
      for (int qq = tid; qq < 1808; qq += 512) {
        const int m = qq / 904, kk = qq % 904;
        hls[m][kk] = (i > 0 && kk < 900)
          ? gload(out1 + ((size_t)srcA*Bn + m)*Hn + kk) : 0.f;
      }
    }
    if (hasB) {
      for (int qq = tid; qq < 1808; qq += 512) {
        const int m = qq / 904, kk = qq % 904;
        h2l[m][kk] = (kk < 900)
          ? gload(h2buf + ((size_t)(s&1)*Bn + m)*Hn + kk) : 0.f;
      }
    }
    __syncthreads();

    if (hasA) {
      #pragma unroll
      for (int ri = 0; ri < 2; ++ri) {
        const int rho = wv_*2 + ri;
        float a0 = 0.f, a1 = 0.f;
        #pragma unroll
        for (int e = 0; e < 4; ++e) {
          const int k = lane*4 + e*256;
          if (k <= Hn-4) {
            a0 += dot4(wAreg[ri][e], *(const float4*)&hls[0][k]);
            a1 += dot4(wAreg[ri][e], *(const float4*)&hls[1][k]);
          }
        }
        a0 = wred(a0); a1 = wred(a1);
        if (lane == 0) {
          gexA[rho][0] = a0 + gls[rho][i*Bn + 0];
          gexA[rho][1] = a1 + gls[rho][i*Bn + 1];
        }
      }
    }

    if (hasB) {
      #pragma unroll
      for (int ri = 0; ri < 2; ++ri) {
        const int rho = wv_*2 + ri;
        float b0 = 0.f, b1 = 0.f;
        #pragma unroll
        for (int e = 0; e < 4; ++e) {
          const int k = lane*4 + e*256;
          if (k <= 896) {
            b0 += dot4(wiR[ri][e], *(const float4*)&hls[0][k]);
            b1 += dot4(wiR[ri][e], *(const float4*)&hls[1][k]);
            b0 += dot4(whR[ri][e], *(const float4*)&h2l[0][k]);
            b1 += dot4(whR[ri][e], *(const float4*)&h2l[1][k]);
          } else if (k >= 900 && k <= 996 && s >= SEQn-2) {
            b0 += dot4(wiR[ri][e], *(const float4*)&wvls[0][k-900]);
            b1 += dot4(wiR[ri][e], *(const float4*)&wvls[1][k-900]);
          }
        }
        b0 = wred(b0); b1 = wred(b1);
        if (lane == 0) {
          const float bb = bls[s][rho];
          gexB[rho][0] = b0 + bb;
          gexB[rho][1] = b1 + bb;
        }
      }
      if (s < 32) ISSUE_W(s+1);
    }

    if (i == 32 || i == 34 || i == 36) {
      const int nout = (i == 34) ? RELn : OBJn;
      const float* wh  = (i == 32) ? wobj1 : (i == 34) ? wrel : wobj2;
      const float* bh_ = (i == 32) ? bobj1 : (i == 34) ? brel : bobj2;
      const int off = (i == 32) ? 0 : (i == 34) ? (Bn*OBJn) : (Bn*OBJn + Bn*RELn);
      const int hb = (i == 34) ? 0 : 1;
      if (blk < nout*Bn) {
        const int o = blk >> 1, m = blk & 1;
        float p = 0.f;
        if (tid < 225) {
          const float4 wv4 = *(const float4*)(wh + (size_t)o*Hn + tid*4);
          float* hp = h2buf + ((size_t)hb*Bn + m)*Hn + tid*4;
          p = wv4.x*gload(hp+0) + wv4.y*gload(hp+1)
            + wv4.z*gload(hp+2) + wv4.w*gload(hp+3);
        }
        if (wv_ < 4) {
          const float pr = wred(p);
          if (lane == 0) red[wv_] = pr;
        }
        __syncthreads();
        if (tid == 0)
          gstore(&dout[off + m*nout + o], red[0]+red[1]+red[2]+red[3] + bh_[o]);
      }
    }

    __syncthreads();
    if (tid < 8) {
      const int jj = tid >> 1, m = tid & 1;
      if (hasA) {
        const float cc = sigf(gexA[4+jj][m])*cA[jj][m]
                       + sigf(gexA[jj][m])*tanhf(gexA[8+jj][m]);
        cA[jj][m] = cc;
        gstore(out1 + ((size_t)i*Bn + m)*Hn + j0 + jj, sigf(gexA[12+jj][m])*tanhf(cc));
      }
      if (hasB) {
        const float cc = sigf(gexB[4+jj][m])*cB[jj][m]
                       + sigf(gexB[jj][m])*tanhf(gexB[8+jj][m]);
        cB[jj][m] = cc;
        gstore(h2buf + ((size_t)((s+1)&1)*Bn + m)*Hn + j0 + jj,
               sigf(gexB[12+jj][m])*tanhf(cc));
      }
    }

    if (i < NITV-1) gbar(bar);
  }
  #undef ISSUE_W
}

extern "C" void kernel_launch(void* const* d_in, const int* in_sizes, int n_in,
                              void* d_out, int out_size, void* d_ws, size_t ws_size,
                              hipStream_t stream)
{
  (void)in_sizes; (void)n_in; (void)out_size; (void)ws_size;
  const float* x     = (const float*)d_in[0];
  const float* wih1  = (const float*)d_in[1];
  const float* whh1  = (const float*)d_in[2];
  const float* bih1  = (const float*)d_in[3];
  const float* bhh1  = (const float*)d_in[4];
  const float* wih2  = (const float*)d_in[5];
  const float* whh2  = (const float*)d_in[6];
  const float* bih2  = (const float*)d_in[7];
  const float* bhh2  = (const float*)d_in[8];
  const float* wobj1 = (const float*)d_in[9];
  const float* bobj1 = (const float*)d_in[10];
  const float* wrel  = (const float*)d_in[11];
  const float* brel  = (const float*)d_in[12];
  const float* wobj2 = (const float*)d_in[13];
  const float* bobj2 = (const float*)d_in[14];
  const float* embed = (const float*)d_in[15];
  float* dout = (float*)d_out;

  float* ws = (float*)d_ws;
  float* G1    = ws;                                  // 3600*66
  float* out1  = G1 + (size_t)G4n*Mn;                 // 33*2*900
  float* h2buf = out1 + (size_t)SEQn*Bn*Hn;           // 2*2*900
  unsigned* bar = (unsigned*)(h2buf + (size_t)2*Bn*Hn);

  hipMemsetAsync(G1, 0, (size_t)G4n*Mn*sizeof(float), stream);
  hipLaunchKernelGGL(k1_mfma, dim3(RB1*KS1), dim3(320), 0, stream, x, wih1, G1, bar);

  void* args[19];
  args[0]  = (void*)&G1;    args[1]  = (void*)&out1;  args[2]  = (void*)&h2buf;
  args[3]  = (void*)&whh1;  args[4]  = (void*)&wih2;  args[5]  = (void*)&whh2;
  args[6]  = (void*)&bih2;  args[7]  = (void*)&bhh2;  args[8]  = (void*)&bih1;
  args[9]  = (void*)&bhh1;  args[10] = (void*)&wobj1; args[11] = (void*)&bobj1;
  args[12] = (void*)&wrel;  args[13] = (void*)&brel;  args[14] = (void*)&wobj2;
  args[15] = (void*)&bobj2; args[16] = (void*)&embed; args[17] = (void*)&dout;
  args[18] = (void*)&bar;
  hipLaunchCooperativeKernel((void*)k_rec, dim3(NBLK), dim3(512), args, 0, stream);
}